// Round 9
// baseline (617.873 us; speedup 1.0000x reference)
//
#include <hip/hip_runtime.h>
#include <hip/hip_bf16.h>

#define N_NODES 100000
#define N_EDGES 500000
#define HID 128
#define NEG_SLOPE 0.2f
#define NB 98           // buckets of 1024 nodes: ceil(100000/1024)

typedef __attribute__((ext_vector_type(8))) short short8v;
typedef __attribute__((ext_vector_type(4))) short short4v;
typedef __attribute__((ext_vector_type(4))) float f32x4;

__device__ __forceinline__ short f2bf(float x) {
    union { float f; unsigned u; } v; v.f = x;
    unsigned r = v.u + 0x7fff + ((v.u >> 16) & 1);  // RNE
    return (short)(r >> 16);
}
__device__ __forceinline__ float bflo(unsigned u) {
    union { unsigned x; float f; } c; c.x = u << 16; return c.f;
}
__device__ __forceinline__ float bfhi(unsigned u) {
    union { unsigned x; float f; } c; c.x = u & 0xffff0000u; return c.f;
}
__device__ __forceinline__ float bfs(short s) {
    union { unsigned x; float f; } c; c.x = ((unsigned)(unsigned short)s) << 16; return c.f;
}

// ---------------- CSR build: binned two-level sort ----------------

__global__ __launch_bounds__(256) void k_bhist(const int* __restrict__ dst, int* __restrict__ bcnt) {
    int r = blockIdx.y, tid = threadIdx.x;
    int base = blockIdx.x * 4096;
    __shared__ int h[128];
    if (tid < 128) h[tid] = 0;
    __syncthreads();
    size_t eb = (size_t)r * N_EDGES;
    int lim = min(base + 4096, N_EDGES);
    for (int e = base + tid; e < lim; e += 256) atomicAdd(&h[dst[eb + e] >> 10], 1);
    __syncthreads();
    if (tid < NB && h[tid]) atomicAdd(&bcnt[r * NB + tid], h[tid]);
}

__global__ void k_bscan(const int* __restrict__ bcnt, int* __restrict__ bptr, int* __restrict__ bcur) {
    int r = blockIdx.x, lane = threadIdx.x;
    int carry = 0;
    for (int base = 0; base < NB; base += 64) {
        int i = base + lane;
        int c = (i < NB) ? bcnt[r * NB + i] : 0;
        int v = c;
        #pragma unroll
        for (int d = 1; d < 64; d <<= 1) { int t = __shfl_up(v, d); if (lane >= d) v += t; }
        int excl = carry + v - c;
        if (i < NB) { bptr[r * (NB + 1) + i] = excl; bcur[r * NB + i] = excl; }
        carry += __shfl(v, 63);
    }
    if (lane == 0) bptr[r * (NB + 1) + NB] = carry;
}

// bin edges into bucket regions of ebin packed as ((dst&1023)<<17 | src)
__global__ __launch_bounds__(256) void k_bin(const int* __restrict__ src, const int* __restrict__ dst,
                                             int* __restrict__ bcur, unsigned* __restrict__ ebin) {
    int r = blockIdx.y, tid = threadIdx.x;
    int base = blockIdx.x * 4096;
    __shared__ int cnt[128], incl[128], gb[128], wcur[128];
    __shared__ uint2 stage[4096];
    if (tid < 128) cnt[tid] = 0;
    __syncthreads();
    int myd[16], mys[16];
    size_t eb = (size_t)r * N_EDGES;
    #pragma unroll
    for (int i = 0; i < 16; i++) {
        int e = base + i * 256 + tid;
        if (e < N_EDGES) {
            int d = dst[eb + e];
            myd[i] = d; mys[i] = src[eb + e];
            atomicAdd(&cnt[d >> 10], 1);
        } else myd[i] = -1;
    }
    __syncthreads();
    if (tid < 128) incl[tid] = cnt[tid];
    __syncthreads();
    for (int d = 1; d < 128; d <<= 1) {
        int t = 0;
        if (tid < 128 && tid >= d) t = incl[tid - d];
        __syncthreads();
        if (tid < 128 && tid >= d) incl[tid] += t;
        __syncthreads();
    }
    if (tid < 128) {
        wcur[tid] = incl[tid] - cnt[tid];
        gb[tid] = (tid < NB && cnt[tid] > 0) ? atomicAdd(&bcur[r * NB + tid], cnt[tid]) : 0;
    }
    __syncthreads();
    #pragma unroll
    for (int i = 0; i < 16; i++) {
        if (myd[i] >= 0) {
            int bkt = myd[i] >> 10;
            int p = atomicAdd(&wcur[bkt], 1);
            stage[p] = make_uint2((unsigned)myd[i], (unsigned)mys[i]);
        }
    }
    __syncthreads();
    int tot = min(4096, N_EDGES - base);
    for (int i = tid; i < tot; i += 256) {
        uint2 u = stage[i];
        int bkt = (int)(u.x >> 10);
        int ex = incl[bkt] - cnt[bkt];
        ebin[eb + gb[bkt] + (i - ex)] = ((u.x & 1023u) << 17) | u.y;
    }
}

__global__ __launch_bounds__(256) void k_nhist(const unsigned* __restrict__ ebin,
                                               const int* __restrict__ bptr,
                                               int* __restrict__ rowptr) {
    int b = blockIdx.x, r = blockIdx.y, tid = threadIdx.x;
    __shared__ int cnt[1024];
    __shared__ int wsum[4];
    for (int i = tid; i < 1024; i += 256) cnt[i] = 0;
    __syncthreads();
    int es = bptr[r * (NB + 1) + b], ee = bptr[r * (NB + 1) + b + 1];
    size_t eb = (size_t)r * N_EDGES;
    for (int i = es + tid; i < ee; i += 256) atomicAdd(&cnt[(ebin[eb + i] >> 17) & 1023u], 1);
    __syncthreads();
    int b4 = tid * 4;
    int c0 = cnt[b4], c1 = cnt[b4 + 1], c2 = cnt[b4 + 2], c3 = cnt[b4 + 3];
    int ts = c0 + c1 + c2 + c3;
    int lane = tid & 63, wid = tid >> 6;
    int v = ts;
    #pragma unroll
    for (int d = 1; d < 64; d <<= 1) { int t = __shfl_up(v, d); if (lane >= d) v += t; }
    if (lane == 63) wsum[wid] = v;
    __syncthreads();
    int woff = 0;
    for (int w = 0; w < wid; w++) woff += wsum[w];
    int p = woff + v - ts;
    int node0 = b << 10;
    int rp = r * (N_NODES + 1);
    int nd;
    nd = node0 + b4;     if (nd < N_NODES) rowptr[rp + nd] = es + p; p += c0;
    nd = node0 + b4 + 1; if (nd < N_NODES) rowptr[rp + nd] = es + p; p += c1;
    nd = node0 + b4 + 2; if (nd < N_NODES) rowptr[rp + nd] = es + p; p += c2;
    nd = node0 + b4 + 3; if (nd < N_NODES) rowptr[rp + nd] = es + p;
    if (b == NB - 1 && tid == 0) rowptr[rp + N_NODES] = bptr[r * (NB + 1) + NB];
}

__global__ __launch_bounds__(256) void k_scat2(const unsigned* __restrict__ ebin,
                                               const int* __restrict__ bptr,
                                               const int* __restrict__ rowptr,
                                               int* __restrict__ csrc) {
    int b = blockIdx.x, r = blockIdx.y, tid = threadIdx.x;
    __shared__ int cnt[1024];
    __shared__ int rloc[1024];
    __shared__ int stage[8192];
    int node0 = b << 10;
    int rp = r * (N_NODES + 1);
    int rs = rowptr[rp + node0];
    for (int i = tid; i < 1024; i += 256) {
        cnt[i] = 0;
        int nd = node0 + i; if (nd > N_NODES) nd = N_NODES;
        rloc[i] = rowptr[rp + nd] - rs;
    }
    __syncthreads();
    int es = bptr[r * (NB + 1) + b], ee = bptr[r * (NB + 1) + b + 1];
    int sz = ee - es;
    size_t eb = (size_t)r * N_EDGES;
    if (sz <= 8192) {
        for (int i = es + tid; i < ee; i += 256) {
            unsigned u = ebin[eb + i];
            int dl = (int)((u >> 17) & 1023u);
            int rk = atomicAdd(&cnt[dl], 1);
            stage[rloc[dl] + rk] = (int)(u & 0x1FFFFu);
        }
        __syncthreads();
        for (int i = tid; i < sz; i += 256) csrc[eb + rs + i] = stage[i];
    } else {
        for (int i = es + tid; i < ee; i += 256) {
            unsigned u = ebin[eb + i];
            int dl = (int)((u >> 17) & 1023u);
            int rk = atomicAdd(&cnt[dl], 1);
            csrc[eb + rs + rloc[dl] + rk] = (int)(u & 0x1FFFFu);
        }
    }
}

// ---------------- W prep: f32 [k][col] -> bf16 [col][k ^ ((col&7)<<3)] ----------------
__global__ void k_wprep(const float* __restrict__ Ws, short* __restrict__ Wt) {
    int i = blockIdx.x * blockDim.x + threadIdx.x;
    if (i < 6 * 16384) {
        int lr = i >> 14, rem = i & 16383, k = rem >> 7, col = rem & 127;
        Wt[lr * 16384 + col * 128 + (k ^ ((col & 7) << 3))] = f2bf(Ws[i]);
    }
}

// clf_W f32 [128 k][64 col] -> bf16 [col][k ^ ((col&7)<<3)]
__global__ void k_wprep2(const float* __restrict__ Wc, short* __restrict__ Wcb) {
    int i = blockIdx.x * blockDim.x + threadIdx.x;
    if (i < 8192) {
        int k = i >> 6, col = i & 63;
        Wcb[col * 128 + (k ^ ((col & 7) << 3))] = f2bf(Wc[i]);
    }
}

// ---------------- wa vectors: wa[lr][comp][k] = sum_d W[lr][k][head*64+d]*a[head][d]; bsum[l][c] ----------------
// comp: 0=el_h0, 1=el_h1, 2=er_h0, 3=er_h1 (matches elr float4 x,y,z,w)
__global__ void k_wa(const float* __restrict__ Ws, const float* __restrict__ als,
                     const float* __restrict__ ars, const float* __restrict__ bs,
                     float* __restrict__ wa, float* __restrict__ bsum) {
    int i = blockIdx.x * blockDim.x + threadIdx.x;
    if (i < 3072) {
        int k = i & 127;
        int comp = (i >> 7) & 3;
        int lr = i >> 9;
        int head = comp & 1, side = comp >> 1;
        const float* a = (side == 0 ? als : ars) + lr * 128 + head * 64;
        const float* w = Ws + ((size_t)lr * 128 + k) * 128 + head * 64;
        float s = 0.f;
        #pragma unroll 8
        for (int d = 0; d < 64; d++) s += w[d] * a[d];
        wa[i] = s;
    } else if (i < 3072 + 256) {
        int j = i - 3072;
        int l = j >> 7, c = j & 127;
        bsum[j] = bs[(l * 3 + 0) * 128 + c] + bs[(l * 3 + 1) * 128 + c] + bs[(l * 3 + 2) * 128 + c];
    }
}

// ---------------- f32 -> bf16 bulk convert ----------------
__global__ void k_cvt(const float* __restrict__ in, short* __restrict__ out, int n) {
    int i = blockIdx.x * blockDim.x + threadIdx.x;
    int stride = gridDim.x * blockDim.x;
    for (int base = i * 8; base < n; base += stride * 8) {
        float4 x = *(const float4*)(in + base);
        float4 y = *(const float4*)(in + base + 4);
        short8v o;
        o[0] = f2bf(x.x); o[1] = f2bf(x.y); o[2] = f2bf(x.z); o[3] = f2bf(x.w);
        o[4] = f2bf(y.x); o[5] = f2bf(y.y); o[6] = f2bf(y.z); o[7] = f2bf(y.w);
        *(short8v*)(out + base) = o;
    }
}

// ---------------- elr from h: el_r[u] = h[u] . wa[r][comp] (12 dots, wave per node) ----------------
__global__ __launch_bounds__(256) void k_eler12(const short* __restrict__ h,
                                                const float* __restrict__ wa,   // [3][4][128] for this layer
                                                float4* __restrict__ elr, int nrows) {
    int wid = threadIdx.x >> 6, lane = threadIdx.x & 63;
    int v = (blockIdx.x << 2) + wid;
    if (v >= nrows) return;
    int c0 = lane << 1;
    unsigned u = *(const unsigned*)(h + (size_t)v * 128 + c0);
    float f0 = bflo(u), f1 = bfhi(u);
    float e[12];
    #pragma unroll
    for (int i = 0; i < 12; i++)
        e[i] = f0 * wa[i * 128 + c0] + f1 * wa[i * 128 + c0 + 1];
    #pragma unroll
    for (int off = 32; off; off >>= 1) {
        #pragma unroll
        for (int i = 0; i < 12; i++) e[i] += __shfl_xor(e[i], off);
    }
    if (lane == 0) {
        #pragma unroll
        for (int r = 0; r < 3; r++)
            elr[(size_t)r * N_NODES + v] = make_float4(e[r * 4], e[r * 4 + 1], e[r * 4 + 2], e[r * 4 + 3]);
    }
}

// ---------------- merged 3-relation softmax + PER-HEAD gather of SHARED h ----------------
// aggh[v][r][hh][c] = (1/s_{r,hh}) * sum_u p^{hh}_u * h[u][c]   (full 128-dim per head!)
// no-max softmax (|e| small). W applied afterward (GEMM distributes; head selects W columns).
__global__ __launch_bounds__(256) void k_agg3h(const short* __restrict__ h,
                                               const float4* __restrict__ elr,   // [3][N]
                                               const int* __restrict__ rowptr,   // [3][N+1]
                                               const int* __restrict__ csrc,     // [3][E]
                                               short* __restrict__ aggh, int nrows) {
    int wid = threadIdx.x >> 6, lane = threadIdx.x & 63;
    int v = (blockIdx.x << 2) + wid;
    if (v >= nrows) return;
    int c0 = lane << 1;

    int beg[3], end[3];
    #pragma unroll
    for (int r = 0; r < 3; r++) {
        beg[r] = rowptr[r * (N_NODES + 1) + v];
        end[r] = rowptr[r * (N_NODES + 1) + v + 1];
    }
    float4 ev[3];
    #pragma unroll
    for (int r = 0; r < 3; r++) ev[r] = elr[(size_t)r * N_NODES + v];

    int sv[3]; float p0[3], p1[3]; int bc[3];
    #pragma unroll
    for (int r = 0; r < 3; r++) {
        int cnt = end[r] - beg[r];
        bc[r] = min(64, cnt);
        sv[r] = (lane < cnt) ? csrc[(size_t)r * N_EDGES + beg[r] + lane] : 0;
    }
    #pragma unroll
    for (int r = 0; r < 3; r++) {
        float4 es = elr[(size_t)r * N_NODES + sv[r]];
        float e0 = es.x + ev[r].z; e0 = e0 >= 0.f ? e0 : NEG_SLOPE * e0;
        float e1 = es.y + ev[r].w; e1 = e1 >= 0.f ? e1 : NEG_SLOPE * e1;
        bool val = lane < (end[r] - beg[r]);
        p0[r] = val ? __expf(e0) : 0.f;
        p1[r] = val ? __expf(e1) : 0.f;
    }

    // a{ch}{head}[r]: ch = c0 / c0+1, head = 0/1
    float a00[3] = {}, a10[3] = {}, a01[3] = {}, a11[3] = {};
    float s0[3] = {}, s1[3] = {};

    auto body = [&](int jj) {
        #pragma unroll
        for (int r = 0; r < 3; r++) {
            if (jj < bc[r]) {   // wave-uniform
                int ss = __shfl(sv[r], jj);
                float q0 = __shfl(p0[r], jj), q1 = __shfl(p1[r], jj);
                unsigned u = *(const unsigned*)(h + ((size_t)ss << 7) + c0);
                float f0 = bflo(u), f1 = bfhi(u);
                s0[r] += q0; s1[r] += q1;
                a00[r] += q0 * f0; a10[r] += q0 * f1;
                a01[r] += q1 * f0; a11[r] += q1 * f1;
            }
        }
    };
    int mb = max(bc[0], max(bc[1], bc[2]));
    int jj = 0;
    for (; jj + 2 <= mb; jj += 2) { body(jj); body(jj + 1); }
    if (jj < mb) body(jj);

    // rare tail: degree > 64
    #pragma unroll
    for (int r = 0; r < 3; r++) {
        for (int base = beg[r] + 64; base < end[r]; base += 64) {
            int idx = base + lane;
            bool val = idx < end[r];
            int sv2 = val ? csrc[(size_t)r * N_EDGES + idx] : 0;
            float4 es = elr[(size_t)r * N_NODES + sv2];
            float e0 = es.x + ev[r].z; e0 = e0 >= 0.f ? e0 : NEG_SLOPE * e0;
            float e1 = es.y + ev[r].w; e1 = e1 >= 0.f ? e1 : NEG_SLOPE * e1;
            float q0v = val ? __expf(e0) : 0.f;
            float q1v = val ? __expf(e1) : 0.f;
            int bc2 = min(64, end[r] - base);
            for (int k = 0; k < bc2; k++) {
                int ss = __shfl(sv2, k);
                float q0 = __shfl(q0v, k), q1 = __shfl(q1v, k);
                unsigned u = *(const unsigned*)(h + ((size_t)ss << 7) + c0);
                float f0 = bflo(u), f1 = bfhi(u);
                s0[r] += q0; s1[r] += q1;
                a00[r] += q0 * f0; a10[r] += q0 * f1;
                a01[r] += q1 * f0; a11[r] += q1 * f1;
            }
        }
    }

    #pragma unroll
    for (int r = 0; r < 3; r++) {
        float inv0 = s0[r] > 0.f ? 1.0f / s0[r] : 0.f;
        float inv1 = s1[r] > 0.f ? 1.0f / s1[r] : 0.f;
        unsigned pk0 = ((unsigned)(unsigned short)f2bf(a00[r] * inv0)) |
                       (((unsigned)(unsigned short)f2bf(a10[r] * inv0)) << 16);
        unsigned pk1 = ((unsigned)(unsigned short)f2bf(a01[r] * inv1)) |
                       (((unsigned)(unsigned short)f2bf(a11[r] * inv1)) << 16);
        *(unsigned*)(aggh + (size_t)v * 768 + r * 256 + c0) = pk0;
        *(unsigned*)(aggh + (size_t)v * 768 + r * 256 + 128 + c0) = pk1;
    }
}

// ---------------- per-head K=384 MFMA GEMM: h_next = relu(sum_r aggh[r,hh] @ W_r[:,hh-half] + bsum) ----------------
__global__ __launch_bounds__(256) void k_gemm768(const short* __restrict__ A,     // aggh [N][3][2][128]
                                                 const short* __restrict__ Wt3,   // 3 x 16384, pre-swizzled
                                                 const float* __restrict__ bsum,  // [128]
                                                 short* __restrict__ outB, int nrows) {
    __shared__ __align__(16) short Wl[128 * 128];
    int tid = threadIdx.x;
    int lane = tid & 63, wid = tid >> 6;
    int q = lane >> 4, j = lane & 15;
    int rowbase = blockIdx.x * 128 + wid * 32;

    f32x4 acc[2][2][4] = {};   // [hh][rb][cb]
    for (int cr = 0; cr < 3; cr++) {
        if (cr) __syncthreads();   // all waves done reading Wl before overwrite
        {
            const float4* srcv = (const float4*)(Wt3 + cr * 16384);
            float4* dstv = (float4*)Wl;
            #pragma unroll
            for (int i = 0; i < 8; i++) dstv[tid + i * 256] = srcv[tid + i * 256];
        }
        short8v a[2][2][4];   // [hh][rb][kk]
        #pragma unroll
        for (int hh = 0; hh < 2; hh++) {
            #pragma unroll
            for (int rb = 0; rb < 2; rb++) {
                int row = rowbase + rb * 16 + j;
                const short* ap = A + (size_t)row * 768 + cr * 256 + hh * 128 + q * 8;
                bool ok = row < nrows;
                #pragma unroll
                for (int kk = 0; kk < 4; kk++)
                    a[hh][rb][kk] = ok ? *(const short8v*)(ap + kk * 32) : (short8v)0;
            }
        }
        __syncthreads();
        #pragma unroll
        for (int hh = 0; hh < 2; hh++) {
            #pragma unroll
            for (int cb = 0; cb < 4; cb++) {
                int col = hh * 64 + cb * 16 + j;
                const short* wp = Wl + col * 128;
                int sw = (col & 7) << 3;
                #pragma unroll
                for (int kk = 0; kk < 4; kk++) {
                    short8v b = *(const short8v*)(wp + ((kk * 32 + q * 8) ^ sw));
                    acc[hh][0][cb] = __builtin_amdgcn_mfma_f32_16x16x32_bf16(a[hh][0][kk], b, acc[hh][0][cb], 0, 0, 0);
                    acc[hh][1][cb] = __builtin_amdgcn_mfma_f32_16x16x32_bf16(a[hh][1][kk], b, acc[hh][1][cb], 0, 0, 0);
                }
            }
        }
    }

    float bv[2][4];
    #pragma unroll
    for (int hh = 0; hh < 2; hh++)
        #pragma unroll
        for (int cb = 0; cb < 4; cb++) bv[hh][cb] = bsum[hh * 64 + cb * 16 + j];
    #pragma unroll
    for (int hh = 0; hh < 2; hh++) {
        #pragma unroll
        for (int rb = 0; rb < 2; rb++) {
            int row0 = rowbase + rb * 16 + q * 4;
            #pragma unroll
            for (int reg = 0; reg < 4; reg++) {
                int row = row0 + reg;
                if (row < nrows) {
                    short* op = outB + (size_t)row * 128 + hh * 64 + j;
                    #pragma unroll
                    for (int cb = 0; cb < 4; cb++)
                        op[cb * 16] = f2bf(fmaxf(acc[hh][rb][cb][reg] + bv[hh][cb], 0.f));
                }
            }
        }
    }
}

// ---------------- BN stats (bf16 relu'd input, vectorized) ----------------
__global__ __launch_bounds__(256) void k_bnstat(const short* __restrict__ h,
                                                float* __restrict__ sums, int nrows) {
    int tid = threadIdx.x;
    int cg = tid & 15, rgrp = tid >> 4;
    float s[8] = {}, q[8] = {};
    for (int row = blockIdx.x * 16 + rgrp; row < nrows; row += gridDim.x * 16) {
        short8v u = *(const short8v*)(h + (size_t)row * 128 + cg * 8);
        #pragma unroll
        for (int i = 0; i < 8; i++) {
            float x = bfs(u[i]);
            s[i] += x; q[i] += x * x;
        }
    }
    __shared__ float ls[16][128];
    __shared__ float lq[16][128];
    #pragma unroll
    for (int i = 0; i < 8; i++) { ls[rgrp][cg * 8 + i] = s[i]; lq[rgrp][cg * 8 + i] = q[i]; }
    __syncthreads();
    int t = tid;
    if (t < 128) {
        float ts = 0.f, tq = 0.f;
        #pragma unroll
        for (int g = 0; g < 16; g++) { ts += ls[g][t]; tq += lq[g][t]; }
        atomicAdd(&sums[t], ts);
        atomicAdd(&sums[128 + t], tq);
    }
}

// ---------------- classifier: BN-normalize (input pre-relu'd bf16) -> MFMA GEMM [N,128]x[128,64] ----------------
__global__ __launch_bounds__(256) void k_clf(const short* __restrict__ h,
                                             const float* __restrict__ sums,
                                             const float* __restrict__ bn_w,
                                             const float* __restrict__ bn_b,
                                             const short* __restrict__ Wcb,
                                             const float* __restrict__ cbias,
                                             float* __restrict__ out, int nrows) {
    __shared__ __align__(16) short Wl[64 * 128];
    __shared__ float2 bnp[128];
    int tid = threadIdx.x;
    {
        const float4* srcv = (const float4*)Wcb;
        float4* dstv = (float4*)Wl;
        #pragma unroll
        for (int i = 0; i < 4; i++) dstv[tid + i * 256] = srcv[tid + i * 256];
    }
    if (tid < 128) {
        float mu = sums[tid] / (float)nrows;
        float var = sums[128 + tid] / (float)nrows - mu * mu;
        float rs = rsqrtf(var + 1e-5f);
        float sc = bn_w[tid] * rs;
        bnp[tid] = make_float2(sc, bn_b[tid] - mu * sc);
    }
    __syncthreads();

    int lane = tid & 63, wid = tid >> 6;
    int q = lane >> 4, j = lane & 15;
    int rowbase = blockIdx.x * 128 + wid * 32;

    float cbv[4];
    #pragma unroll
    for (int cb = 0; cb < 4; cb++) cbv[cb] = cbias[cb * 16 + j];

    short8v a[2][4];
    #pragma unroll
    for (int rb = 0; rb < 2; rb++) {
        int row = rowbase + rb * 16 + j;
        bool ok = row < nrows;
        const short* hp = h + (size_t)row * 128 + q * 8;
        #pragma unroll
        for (int kk = 0; kk < 4; kk++) {
            short8v u = ok ? *(const short8v*)(hp + kk * 32) : (short8v)0;
            int k0 = kk * 32 + q * 8;
            short8v av;
            #pragma unroll
            for (int i = 0; i < 8; i++) {
                float2 bp = bnp[k0 + i];
                av[i] = f2bf(bfs(u[i]) * bp.x + bp.y);
            }
            a[rb][kk] = av;
        }
    }

    f32x4 acc[2][4] = {};
    #pragma unroll
    for (int cb = 0; cb < 4; cb++) {
        int col = cb * 16 + j;
        const short* wp = Wl + col * 128;
        int sw = (col & 7) << 3;
        #pragma unroll
        for (int kk = 0; kk < 4; kk++) {
            short8v b = *(const short8v*)(wp + ((kk * 32 + q * 8) ^ sw));
            acc[0][cb] = __builtin_amdgcn_mfma_f32_16x16x32_bf16(a[0][kk], b, acc[0][cb], 0, 0, 0);
            acc[1][cb] = __builtin_amdgcn_mfma_f32_16x16x32_bf16(a[1][kk], b, acc[1][cb], 0, 0, 0);
        }
    }

    #pragma unroll
    for (int rb = 0; rb < 2; rb++) {
        int row0 = rowbase + rb * 16 + q * 4;
        #pragma unroll
        for (int reg = 0; reg < 4; reg++) {
            int row = row0 + reg;
            if (row < nrows) {
                float* op = out + (size_t)row * 64 + j;
                #pragma unroll
                for (int cb = 0; cb < 4; cb++) op[cb * 16] = acc[rb][cb][reg] + cbv[cb];
            }
        }
    }
}

// ---------------- launch ----------------

extern "C" void kernel_launch(void* const* d_in, const int* in_sizes, int n_in,
                              void* d_out, int out_size, void* d_ws, size_t ws_size,
                              hipStream_t stream) {
    (void)in_sizes; (void)n_in; (void)out_size; (void)ws_size;
    const float* feat_in = (const float*)d_in[0];
    const float* Ws      = (const float*)d_in[1];
    const float* als     = (const float*)d_in[2];
    const float* ars     = (const float*)d_in[3];
    const float* bs      = (const float*)d_in[4];
    const float* bn_w    = (const float*)d_in[5];
    const float* bn_b    = (const float*)d_in[6];
    const float* clf_W   = (const float*)d_in[7];
    const float* clf_b   = (const float*)d_in[8];
    const int*   src     = (const int*)d_in[9];
    const int*   dst     = (const int*)d_in[10];
    float* out = (float*)d_out;

    const int N = N_NODES, E = N_EDGES;
    char* p = (char*)d_ws;
    auto carve = [&](size_t bytes) { char* q = p; p += (bytes + 255) & ~255ULL; return q; };
    int*      bcnt   = (int*)carve((size_t)3 * NB * 4);
    int*      bptr   = (int*)carve((size_t)3 * (NB + 1) * 4);
    int*      bcur   = (int*)carve((size_t)3 * NB * 4);
    int*      rowptr = (int*)carve((size_t)3 * (N + 1) * 4);
    int*      csrc   = (int*)carve((size_t)3 * E * 4);
    float4*   elr    = (float4*)carve((size_t)3 * N * 16);
    float*    bnsum  = (float*)carve(256 * 4);
    float*    wa     = (float*)carve((size_t)6 * 4 * 128 * 4);
    float*    bsum   = (float*)carve((size_t)2 * 128 * 4);
    short*    Wtg    = (short*)carve((size_t)6 * 16384 * 2);
    short*    Wcb    = (short*)carve((size_t)8192 * 2);
    short*    hA     = (short*)carve((size_t)N * 128 * 2);
    short*    hB     = (short*)carve((size_t)N * 128 * 2);
    short*    aggh   = (short*)carve((size_t)N * 768 * 2);
    // ebin only needed during CSR build, before aggh is first written -> alias into aggh
    unsigned* ebin   = (unsigned*)aggh;   // needs 3*E*4 = 6 MB << 153.6 MB

    // weight prep + input conversion
    k_wprep<<<(6 * 16384 + 255) / 256, 256, 0, stream>>>(Ws, Wtg);
    k_wprep2<<<32, 256, 0, stream>>>(clf_W, Wcb);
    k_wa<<<(3072 + 256 + 255) / 256, 256, 0, stream>>>(Ws, als, ars, bs, wa, bsum);
    k_cvt<<<2048, 256, 0, stream>>>(feat_in, hA, N * 128);

    // CSR build via binned sort
    hipMemsetAsync(bcnt, 0, (size_t)3 * NB * 4, stream);
    dim3 gchunk((E + 4095) / 4096, 3);
    k_bhist<<<gchunk, 256, 0, stream>>>(dst, bcnt);
    k_bscan<<<3, 64, 0, stream>>>(bcnt, bptr, bcur);
    k_bin<<<gchunk, 256, 0, stream>>>(src, dst, bcur, ebin);
    dim3 gbkt(NB, 3);
    k_nhist<<<gbkt, 256, 0, stream>>>(ebin, bptr, rowptr);
    k_scat2<<<gbkt, 256, 0, stream>>>(ebin, bptr, rowptr, csrc);

    int gq = (N + 3) / 4;
    // layer 0
    k_eler12<<<gq, 256, 0, stream>>>(hA, wa, elr, N);
    k_agg3h<<<gq, 256, 0, stream>>>(hA, elr, rowptr, csrc, aggh, N);
    k_gemm768<<<(N + 127) / 128, 256, 0, stream>>>(aggh, Wtg, bsum, hB, N);
    // layer 1
    k_eler12<<<gq, 256, 0, stream>>>(hB, wa + 12 * 128, elr, N);
    k_agg3h<<<gq, 256, 0, stream>>>(hB, elr, rowptr, csrc, aggh, N);
    k_gemm768<<<(N + 127) / 128, 256, 0, stream>>>(aggh, Wtg + 3 * 16384, bsum + 128, hA, N);

    // BN + classifier on hA
    hipMemsetAsync(bnsum, 0, 256 * 4, stream);
    k_bnstat<<<512, 256, 0, stream>>>(hA, bnsum, N);
    k_clf<<<(N + 127) / 128, 256, 0, stream>>>(hA, bnsum, bn_w, bn_b, Wcb, clf_b, out, N);
}

// Round 10
// 448.395 us; speedup vs baseline: 1.3780x; 1.3780x over previous
//
#include <hip/hip_runtime.h>
#include <hip/hip_bf16.h>

#define N_NODES 100000
#define N_EDGES 500000
#define HID 128
#define NEG_SLOPE 0.2f
#define NB 98           // buckets of 1024 nodes: ceil(100000/1024)

typedef __attribute__((ext_vector_type(8))) short short8v;
typedef __attribute__((ext_vector_type(4))) short short4v;
typedef __attribute__((ext_vector_type(4))) float f32x4;

__device__ __forceinline__ short f2bf(float x) {
    union { float f; unsigned u; } v; v.f = x;
    unsigned r = v.u + 0x7fff + ((v.u >> 16) & 1);  // RNE
    return (short)(r >> 16);
}
__device__ __forceinline__ float bflo(unsigned u) {
    union { unsigned x; float f; } c; c.x = u << 16; return c.f;
}
__device__ __forceinline__ float bfhi(unsigned u) {
    union { unsigned x; float f; } c; c.x = u & 0xffff0000u; return c.f;
}
__device__ __forceinline__ float bfs(short s) {
    union { unsigned x; float f; } c; c.x = ((unsigned)(unsigned short)s) << 16; return c.f;
}
__device__ __forceinline__ float asf(unsigned u) {
    union { unsigned x; float f; } c; c.x = u; return c.f;
}

// ---------------- CSR build: binned two-level sort ----------------

__global__ __launch_bounds__(256) void k_bhist(const int* __restrict__ dst, int* __restrict__ bcnt) {
    int r = blockIdx.y, tid = threadIdx.x;
    int base = blockIdx.x * 4096;
    __shared__ int h[128];
    if (tid < 128) h[tid] = 0;
    __syncthreads();
    size_t eb = (size_t)r * N_EDGES;
    int lim = min(base + 4096, N_EDGES);
    for (int e = base + tid; e < lim; e += 256) atomicAdd(&h[dst[eb + e] >> 10], 1);
    __syncthreads();
    if (tid < NB && h[tid]) atomicAdd(&bcnt[r * NB + tid], h[tid]);
}

__global__ void k_bscan(const int* __restrict__ bcnt, int* __restrict__ bptr, int* __restrict__ bcur) {
    int r = blockIdx.x, lane = threadIdx.x;
    int carry = 0;
    for (int base = 0; base < NB; base += 64) {
        int i = base + lane;
        int c = (i < NB) ? bcnt[r * NB + i] : 0;
        int v = c;
        #pragma unroll
        for (int d = 1; d < 64; d <<= 1) { int t = __shfl_up(v, d); if (lane >= d) v += t; }
        int excl = carry + v - c;
        if (i < NB) { bptr[r * (NB + 1) + i] = excl; bcur[r * NB + i] = excl; }
        carry += __shfl(v, 63);
    }
    if (lane == 0) bptr[r * (NB + 1) + NB] = carry;
}

// bin edges into bucket regions of ebin packed as ((dst&1023)<<17 | src)
__global__ __launch_bounds__(256) void k_bin(const int* __restrict__ src, const int* __restrict__ dst,
                                             int* __restrict__ bcur, unsigned* __restrict__ ebin) {
    int r = blockIdx.y, tid = threadIdx.x;
    int base = blockIdx.x * 4096;
    __shared__ int cnt[128], incl[128], gb[128], wcur[128];
    __shared__ uint2 stage[4096];
    if (tid < 128) cnt[tid] = 0;
    __syncthreads();
    int myd[16], mys[16];
    size_t eb = (size_t)r * N_EDGES;
    #pragma unroll
    for (int i = 0; i < 16; i++) {
        int e = base + i * 256 + tid;
        if (e < N_EDGES) {
            int d = dst[eb + e];
            myd[i] = d; mys[i] = src[eb + e];
            atomicAdd(&cnt[d >> 10], 1);
        } else myd[i] = -1;
    }
    __syncthreads();
    if (tid < 128) incl[tid] = cnt[tid];
    __syncthreads();
    for (int d = 1; d < 128; d <<= 1) {
        int t = 0;
        if (tid < 128 && tid >= d) t = incl[tid - d];
        __syncthreads();
        if (tid < 128 && tid >= d) incl[tid] += t;
        __syncthreads();
    }
    if (tid < 128) {
        wcur[tid] = incl[tid] - cnt[tid];
        gb[tid] = (tid < NB && cnt[tid] > 0) ? atomicAdd(&bcur[r * NB + tid], cnt[tid]) : 0;
    }
    __syncthreads();
    #pragma unroll
    for (int i = 0; i < 16; i++) {
        if (myd[i] >= 0) {
            int bkt = myd[i] >> 10;
            int p = atomicAdd(&wcur[bkt], 1);
            stage[p] = make_uint2((unsigned)myd[i], (unsigned)mys[i]);
        }
    }
    __syncthreads();
    int tot = min(4096, N_EDGES - base);
    for (int i = tid; i < tot; i += 256) {
        uint2 u = stage[i];
        int bkt = (int)(u.x >> 10);
        int ex = incl[bkt] - cnt[bkt];
        ebin[eb + gb[bkt] + (i - ex)] = ((u.x & 1023u) << 17) | u.y;
    }
}

__global__ __launch_bounds__(256) void k_nhist(const unsigned* __restrict__ ebin,
                                               const int* __restrict__ bptr,
                                               int* __restrict__ rowptr) {
    int b = blockIdx.x, r = blockIdx.y, tid = threadIdx.x;
    __shared__ int cnt[1024];
    __shared__ int wsum[4];
    for (int i = tid; i < 1024; i += 256) cnt[i] = 0;
    __syncthreads();
    int es = bptr[r * (NB + 1) + b], ee = bptr[r * (NB + 1) + b + 1];
    size_t eb = (size_t)r * N_EDGES;
    for (int i = es + tid; i < ee; i += 256) atomicAdd(&cnt[(ebin[eb + i] >> 17) & 1023u], 1);
    __syncthreads();
    int b4 = tid * 4;
    int c0 = cnt[b4], c1 = cnt[b4 + 1], c2 = cnt[b4 + 2], c3 = cnt[b4 + 3];
    int ts = c0 + c1 + c2 + c3;
    int lane = tid & 63, wid = tid >> 6;
    int v = ts;
    #pragma unroll
    for (int d = 1; d < 64; d <<= 1) { int t = __shfl_up(v, d); if (lane >= d) v += t; }
    if (lane == 63) wsum[wid] = v;
    __syncthreads();
    int woff = 0;
    for (int w = 0; w < wid; w++) woff += wsum[w];
    int p = woff + v - ts;
    int node0 = b << 10;
    int rp = r * (N_NODES + 1);
    int nd;
    nd = node0 + b4;     if (nd < N_NODES) rowptr[rp + nd] = es + p; p += c0;
    nd = node0 + b4 + 1; if (nd < N_NODES) rowptr[rp + nd] = es + p; p += c1;
    nd = node0 + b4 + 2; if (nd < N_NODES) rowptr[rp + nd] = es + p; p += c2;
    nd = node0 + b4 + 3; if (nd < N_NODES) rowptr[rp + nd] = es + p;
    if (b == NB - 1 && tid == 0) rowptr[rp + N_NODES] = bptr[r * (NB + 1) + NB];
}

__global__ __launch_bounds__(256) void k_scat2(const unsigned* __restrict__ ebin,
                                               const int* __restrict__ bptr,
                                               const int* __restrict__ rowptr,
                                               int* __restrict__ csrc) {
    int b = blockIdx.x, r = blockIdx.y, tid = threadIdx.x;
    __shared__ int cnt[1024];
    __shared__ int rloc[1024];
    __shared__ int stage[8192];
    int node0 = b << 10;
    int rp = r * (N_NODES + 1);
    int rs = rowptr[rp + node0];
    for (int i = tid; i < 1024; i += 256) {
        cnt[i] = 0;
        int nd = node0 + i; if (nd > N_NODES) nd = N_NODES;
        rloc[i] = rowptr[rp + nd] - rs;
    }
    __syncthreads();
    int es = bptr[r * (NB + 1) + b], ee = bptr[r * (NB + 1) + b + 1];
    int sz = ee - es;
    size_t eb = (size_t)r * N_EDGES;
    if (sz <= 8192) {
        for (int i = es + tid; i < ee; i += 256) {
            unsigned u = ebin[eb + i];
            int dl = (int)((u >> 17) & 1023u);
            int rk = atomicAdd(&cnt[dl], 1);
            stage[rloc[dl] + rk] = (int)(u & 0x1FFFFu);
        }
        __syncthreads();
        for (int i = tid; i < sz; i += 256) csrc[eb + rs + i] = stage[i];
    } else {
        for (int i = es + tid; i < ee; i += 256) {
            unsigned u = ebin[eb + i];
            int dl = (int)((u >> 17) & 1023u);
            int rk = atomicAdd(&cnt[dl], 1);
            csrc[eb + rs + rloc[dl] + rk] = (int)(u & 0x1FFFFu);
        }
    }
}

// ---------------- W prep: f32 [k][col] -> bf16 [col][k ^ ((col&7)<<3)] ----------------
__global__ void k_wprep(const float* __restrict__ Ws, short* __restrict__ Wt) {
    int i = blockIdx.x * blockDim.x + threadIdx.x;
    if (i < 6 * 16384) {
        int lr = i >> 14, rem = i & 16383, k = rem >> 7, col = rem & 127;
        Wt[lr * 16384 + col * 128 + (k ^ ((col & 7) << 3))] = f2bf(Ws[i]);
    }
}

// clf_W f32 [128 k][64 col] -> bf16 [col][k ^ ((col&7)<<3)]
__global__ void k_wprep2(const float* __restrict__ Wc, short* __restrict__ Wcb) {
    int i = blockIdx.x * blockDim.x + threadIdx.x;
    if (i < 8192) {
        int k = i >> 6, col = i & 63;
        Wcb[col * 128 + (k ^ ((col & 7) << 3))] = f2bf(Wc[i]);
    }
}

// ---------------- f32 -> bf16 bulk convert ----------------
__global__ void k_cvt(const float* __restrict__ in, short* __restrict__ out, int n) {
    int i = blockIdx.x * blockDim.x + threadIdx.x;
    int stride = gridDim.x * blockDim.x;
    for (int base = i * 8; base < n; base += stride * 8) {
        float4 x = *(const float4*)(in + base);
        float4 y = *(const float4*)(in + base + 4);
        short8v o;
        o[0] = f2bf(x.x); o[1] = f2bf(x.y); o[2] = f2bf(x.z); o[3] = f2bf(x.w);
        o[4] = f2bf(y.x); o[5] = f2bf(y.y); o[6] = f2bf(y.z); o[7] = f2bf(y.w);
        *(short8v*)(out + base) = o;
    }
}

// ---------------- MFMA GEMM over 3 relations in one dispatch: featb[r] bf16 + fused el/er ----------------
__global__ __launch_bounds__(256) void k_gemm3(const short* __restrict__ Abf,
                                               const short* __restrict__ Wt3,    // 3 x 16384, pre-swizzled
                                               const float* __restrict__ al3,    // [3][128]
                                               const float* __restrict__ ar3,    // [3][128]
                                               short* __restrict__ featb,        // [3][N*128]
                                               float4* __restrict__ elr,         // [3][N]
                                               int nrows) {
    __shared__ __align__(16) short Wl[128 * 128];
    int tid = threadIdx.x;
    int lane = tid & 63, wid = tid >> 6;
    int q = lane >> 4, j = lane & 15;
    int rowbase = blockIdx.x * 128 + wid * 32;

    // A fragments once (shared by all 3 relations)
    short8v a[2][4];
    #pragma unroll
    for (int rb = 0; rb < 2; rb++) {
        int row = rowbase + rb * 16 + j;
        const short* ap = Abf + (size_t)row * 128 + q * 8;
        bool ok = row < nrows;
        #pragma unroll
        for (int kk = 0; kk < 4; kk++)
            a[rb][kk] = ok ? *(const short8v*)(ap + kk * 32) : (short8v)0;
    }

    for (int cr = 0; cr < 3; cr++) {
        if (cr) __syncthreads();   // all waves done reading Wl before overwrite
        {
            const float4* srcv = (const float4*)(Wt3 + cr * 16384);
            float4* dstv = (float4*)Wl;
            #pragma unroll
            for (int i = 0; i < 8; i++) dstv[tid + i * 256] = srcv[tid + i * 256];
        }
        float alv[8], arv[8];
        #pragma unroll
        for (int cb = 0; cb < 8; cb++) {
            alv[cb] = al3[cr * 128 + cb * 16 + j];
            arv[cb] = ar3[cr * 128 + cb * 16 + j];
        }
        __syncthreads();

        f32x4 acc[2][8] = {};
        #pragma unroll
        for (int cb = 0; cb < 8; cb++) {
            int col = cb * 16 + j;
            const short* wp = Wl + col * 128;
            int sw = (col & 7) << 3;
            #pragma unroll
            for (int kk = 0; kk < 4; kk++) {
                short8v b = *(const short8v*)(wp + ((kk * 32 + q * 8) ^ sw));
                acc[0][cb] = __builtin_amdgcn_mfma_f32_16x16x32_bf16(a[0][kk], b, acc[0][cb], 0, 0, 0);
                acc[1][cb] = __builtin_amdgcn_mfma_f32_16x16x32_bf16(a[1][kk], b, acc[1][cb], 0, 0, 0);
            }
        }

        short* outB = featb + (size_t)cr * N_NODES * 128;
        #pragma unroll
        for (int rb = 0; rb < 2; rb++) {
            int row0 = rowbase + rb * 16 + q * 4;
            #pragma unroll
            for (int reg = 0; reg < 4; reg++) {
                int row = row0 + reg;
                if (row < nrows) {
                    short* op = outB + (size_t)row * 128 + j;
                    #pragma unroll
                    for (int cb = 0; cb < 8; cb++) op[cb * 16] = f2bf(acc[rb][cb][reg]);
                }
            }
        }

        // fused el/er
        float4* elro = elr + (size_t)cr * N_NODES;
        #pragma unroll
        for (int rb = 0; rb < 2; rb++) {
            float e0[4], e1[4], r0[4], r1[4];
            #pragma unroll
            for (int reg = 0; reg < 4; reg++) {
                float se0 = 0.f, se1 = 0.f, sr0 = 0.f, sr1 = 0.f;
                #pragma unroll
                for (int cb = 0; cb < 4; cb++) {
                    se0 += acc[rb][cb][reg] * alv[cb];
                    sr0 += acc[rb][cb][reg] * arv[cb];
                    se1 += acc[rb][cb + 4][reg] * alv[cb + 4];
                    sr1 += acc[rb][cb + 4][reg] * arv[cb + 4];
                }
                #pragma unroll
                for (int off = 1; off < 16; off <<= 1) {
                    se0 += __shfl_xor(se0, off);
                    se1 += __shfl_xor(se1, off);
                    sr0 += __shfl_xor(sr0, off);
                    sr1 += __shfl_xor(sr1, off);
                }
                e0[reg] = se0; e1[reg] = se1; r0[reg] = sr0; r1[reg] = sr1;
            }
            if (j < 4) {
                int row = rowbase + rb * 16 + q * 4 + j;
                if (row < nrows) {
                    float4 v;
                    v.x = j == 0 ? e0[0] : j == 1 ? e0[1] : j == 2 ? e0[2] : e0[3];
                    v.y = j == 0 ? e1[0] : j == 1 ? e1[1] : j == 2 ? e1[2] : e1[3];
                    v.z = j == 0 ? r0[0] : j == 1 ? r0[1] : j == 2 ? r0[2] : r0[3];
                    v.w = j == 0 ? r1[0] : j == 1 ? r1[1] : j == 2 ? r1[2] : r1[3];
                    elro[row] = v;
                }
            }
        }
    }
}

// ---------------- merged 3-relation softmax + gather-aggregate (wave per dst node) ----------------
// no-max softmax; p packed as bf16 pair -> ONE readlane broadcast; src via readlane (scalar addr).
// output: relu'd bf16 h_next (biases of the 3 relations summed in).
__global__ __launch_bounds__(256) void k_agg3(const short* __restrict__ feat,   // [3][N*128]
                                              const float4* __restrict__ elr,   // [3][N]
                                              const int* __restrict__ rowptr,   // [3][N+1]
                                              const int* __restrict__ csrc,     // [3][E]
                                              const float* __restrict__ bias,   // [3][128]
                                              short* __restrict__ outB, int nrows) {
    int wid = threadIdx.x >> 6, lane = threadIdx.x & 63;
    int v = (blockIdx.x << 2) + wid;
    if (v >= nrows) return;
    int c0 = lane << 1;

    int beg[3], end[3], bc[3];
    #pragma unroll
    for (int r = 0; r < 3; r++) {
        beg[r] = rowptr[r * (N_NODES + 1) + v];
        end[r] = rowptr[r * (N_NODES + 1) + v + 1];
        bc[r] = min(64, end[r] - beg[r]);
    }
    float4 ev[3];
    #pragma unroll
    for (int r = 0; r < 3; r++) ev[r] = elr[(size_t)r * N_NODES + v];

    int sv[3]; unsigned pk[3];
    #pragma unroll
    for (int r = 0; r < 3; r++)
        sv[r] = (lane < end[r] - beg[r]) ? csrc[(size_t)r * N_EDGES + beg[r] + lane] : 0;
    #pragma unroll
    for (int r = 0; r < 3; r++) {
        float4 es = elr[(size_t)r * N_NODES + sv[r]];
        float e0 = es.x + ev[r].z; e0 = e0 >= 0.f ? e0 : NEG_SLOPE * e0;
        float e1 = es.y + ev[r].w; e1 = e1 >= 0.f ? e1 : NEG_SLOPE * e1;
        bool val = lane < (end[r] - beg[r]);
        float p0 = val ? __expf(e0) : 0.f;
        float p1 = val ? __expf(e1) : 0.f;
        pk[r] = ((unsigned)(unsigned short)f2bf(p0)) |
                (((unsigned)(unsigned short)f2bf(p1)) << 16);
    }

    float a0[3] = {}, a1[3] = {}, sp[3] = {};

    auto body = [&](int jj) {
        #pragma unroll
        for (int r = 0; r < 3; r++) {
            if (jj < bc[r]) {   // wave-uniform
                int ss = __builtin_amdgcn_readlane(sv[r], jj);
                unsigned pb = (unsigned)__builtin_amdgcn_readlane((int)pk[r], jj);
                // lanes 0-31: head0 (lo bf16), lanes 32-63: head1 (hi bf16)
                unsigned psel = (lane < 32) ? (pb << 16) : (pb & 0xffff0000u);
                float pp = asf(psel);
                unsigned u = *(const unsigned*)(feat + (size_t)r * N_NODES * 128 + ((size_t)ss << 7) + c0);
                sp[r] += pp;
                a0[r] += pp * bflo(u);
                a1[r] += pp * bfhi(u);
            }
        }
    };
    int mb = max(bc[0], max(bc[1], bc[2]));
    int jj = 0;
    for (; jj + 2 <= mb; jj += 2) { body(jj); body(jj + 1); }
    if (jj < mb) body(jj);

    // rare tail: degree > 64 (plain shfl path)
    #pragma unroll
    for (int r = 0; r < 3; r++) {
        for (int base = beg[r] + 64; base < end[r]; base += 64) {
            int idx = base + lane;
            bool val = idx < end[r];
            int sv2 = val ? csrc[(size_t)r * N_EDGES + idx] : 0;
            float4 es = elr[(size_t)r * N_NODES + sv2];
            float e0 = es.x + ev[r].z; e0 = e0 >= 0.f ? e0 : NEG_SLOPE * e0;
            float e1 = es.y + ev[r].w; e1 = e1 >= 0.f ? e1 : NEG_SLOPE * e1;
            float q0v = val ? __expf(e0) : 0.f;
            float q1v = val ? __expf(e1) : 0.f;
            int bc2 = min(64, end[r] - base);
            for (int k = 0; k < bc2; k++) {
                int ss = __builtin_amdgcn_readlane(sv2, k);
                float q0 = asf((unsigned)__builtin_amdgcn_readlane((int)__float_as_uint(q0v), k));
                float q1 = asf((unsigned)__builtin_amdgcn_readlane((int)__float_as_uint(q1v), k));
                float pp = lane < 32 ? q0 : q1;
                unsigned u = *(const unsigned*)(feat + (size_t)r * N_NODES * 128 + ((size_t)ss << 7) + c0);
                sp[r] += pp;
                a0[r] += pp * bflo(u);
                a1[r] += pp * bfhi(u);
            }
        }
    }

    float t0 = bias[c0] + bias[128 + c0] + bias[256 + c0];
    float t1 = bias[c0 + 1] + bias[128 + c0 + 1] + bias[256 + c0 + 1];
    #pragma unroll
    for (int r = 0; r < 3; r++) {
        float inv = sp[r] > 0.f ? 1.0f / sp[r] : 0.f;
        t0 += a0[r] * inv;
        t1 += a1[r] * inv;
    }
    unsigned pko = ((unsigned)(unsigned short)f2bf(fmaxf(t0, 0.f))) |
                   (((unsigned)(unsigned short)f2bf(fmaxf(t1, 0.f))) << 16);
    *(unsigned*)(outB + (size_t)v * 128 + c0) = pko;
}

// ---------------- BN stats (bf16 relu'd input, vectorized) ----------------
__global__ __launch_bounds__(256) void k_bnstat(const short* __restrict__ h,
                                                float* __restrict__ sums, int nrows) {
    int tid = threadIdx.x;
    int cg = tid & 15, rgrp = tid >> 4;
    float s[8] = {}, q[8] = {};
    for (int row = blockIdx.x * 16 + rgrp; row < nrows; row += gridDim.x * 16) {
        short8v u = *(const short8v*)(h + (size_t)row * 128 + cg * 8);
        #pragma unroll
        for (int i = 0; i < 8; i++) {
            float x = bfs(u[i]);
            s[i] += x; q[i] += x * x;
        }
    }
    __shared__ float ls[16][128];
    __shared__ float lq[16][128];
    #pragma unroll
    for (int i = 0; i < 8; i++) { ls[rgrp][cg * 8 + i] = s[i]; lq[rgrp][cg * 8 + i] = q[i]; }
    __syncthreads();
    int t = tid;
    if (t < 128) {
        float ts = 0.f, tq = 0.f;
        #pragma unroll
        for (int g = 0; g < 16; g++) { ts += ls[g][t]; tq += lq[g][t]; }
        atomicAdd(&sums[t], ts);
        atomicAdd(&sums[128 + t], tq);
    }
}

// ---------------- classifier: BN-normalize (input pre-relu'd bf16) -> MFMA GEMM [N,128]x[128,64] ----------------
__global__ __launch_bounds__(256) void k_clf(const short* __restrict__ h,
                                             const float* __restrict__ sums,
                                             const float* __restrict__ bn_w,
                                             const float* __restrict__ bn_b,
                                             const short* __restrict__ Wcb,
                                             const float* __restrict__ cbias,
                                             float* __restrict__ out, int nrows) {
    __shared__ __align__(16) short Wl[64 * 128];
    __shared__ float2 bnp[128];
    int tid = threadIdx.x;
    {
        const float4* srcv = (const float4*)Wcb;
        float4* dstv = (float4*)Wl;
        #pragma unroll
        for (int i = 0; i < 4; i++) dstv[tid + i * 256] = srcv[tid + i * 256];
    }
    if (tid < 128) {
        float mu = sums[tid] / (float)nrows;
        float var = sums[128 + tid] / (float)nrows - mu * mu;
        float rs = rsqrtf(var + 1e-5f);
        float sc = bn_w[tid] * rs;
        bnp[tid] = make_float2(sc, bn_b[tid] - mu * sc);
    }
    __syncthreads();

    int lane = tid & 63, wid = tid >> 6;
    int q = lane >> 4, j = lane & 15;
    int rowbase = blockIdx.x * 128 + wid * 32;

    float cbv[4];
    #pragma unroll
    for (int cb = 0; cb < 4; cb++) cbv[cb] = cbias[cb * 16 + j];

    short8v a[2][4];
    #pragma unroll
    for (int rb = 0; rb < 2; rb++) {
        int row = rowbase + rb * 16 + j;
        bool ok = row < nrows;
        const short* hp = h + (size_t)row * 128 + q * 8;
        #pragma unroll
        for (int kk = 0; kk < 4; kk++) {
            short8v u = ok ? *(const short8v*)(hp + kk * 32) : (short8v)0;
            int k0 = kk * 32 + q * 8;
            short8v av;
            #pragma unroll
            for (int i = 0; i < 8; i++) {
                float2 bp = bnp[k0 + i];
                av[i] = f2bf(bfs(u[i]) * bp.x + bp.y);
            }
            a[rb][kk] = av;
        }
    }

    f32x4 acc[2][4] = {};
    #pragma unroll
    for (int cb = 0; cb < 4; cb++) {
        int col = cb * 16 + j;
        const short* wp = Wl + col * 128;
        int sw = (col & 7) << 3;
        #pragma unroll
        for (int kk = 0; kk < 4; kk++) {
            short8v b = *(const short8v*)(wp + ((kk * 32 + q * 8) ^ sw));
            acc[0][cb] = __builtin_amdgcn_mfma_f32_16x16x32_bf16(a[0][kk], b, acc[0][cb], 0, 0, 0);
            acc[1][cb] = __builtin_amdgcn_mfma_f32_16x16x32_bf16(a[1][kk], b, acc[1][cb], 0, 0, 0);
        }
    }

    #pragma unroll
    for (int rb = 0; rb < 2; rb++) {
        int row0 = rowbase + rb * 16 + q * 4;
        #pragma unroll
        for (int reg = 0; reg < 4; reg++) {
            int row = row0 + reg;
            if (row < nrows) {
                float* op = out + (size_t)row * 64 + j;
                #pragma unroll
                for (int cb = 0; cb < 4; cb++) op[cb * 16] = acc[rb][cb][reg] + cbv[cb];
            }
        }
    }
}

// ---------------- launch ----------------

extern "C" void kernel_launch(void* const* d_in, const int* in_sizes, int n_in,
                              void* d_out, int out_size, void* d_ws, size_t ws_size,
                              hipStream_t stream) {
    (void)in_sizes; (void)n_in; (void)out_size; (void)ws_size;
    const float* feat_in = (const float*)d_in[0];
    const float* Ws      = (const float*)d_in[1];
    const float* als     = (const float*)d_in[2];
    const float* ars     = (const float*)d_in[3];
    const float* bs      = (const float*)d_in[4];
    const float* bn_w    = (const float*)d_in[5];
    const float* bn_b    = (const float*)d_in[6];
    const float* clf_W   = (const float*)d_in[7];
    const float* clf_b   = (const float*)d_in[8];
    const int*   src     = (const int*)d_in[9];
    const int*   dst     = (const int*)d_in[10];
    float* out = (float*)d_out;

    const int N = N_NODES, E = N_EDGES;
    char* p = (char*)d_ws;
    auto carve = [&](size_t bytes) { char* q = p; p += (bytes + 255) & ~255ULL; return q; };
    int*      bcnt   = (int*)carve((size_t)3 * NB * 4);
    int*      bptr   = (int*)carve((size_t)3 * (NB + 1) * 4);
    int*      bcur   = (int*)carve((size_t)3 * NB * 4);
    int*      rowptr = (int*)carve((size_t)3 * (N + 1) * 4);
    int*      csrc   = (int*)carve((size_t)3 * E * 4);
    unsigned* ebin   = (unsigned*)carve((size_t)3 * E * 4);
    float4*   elr    = (float4*)carve((size_t)3 * N * 16);
    float*    bnsum  = (float*)carve(256 * 4);
    short*    Wtg    = (short*)carve((size_t)6 * 16384 * 2);
    short*    Wcb    = (short*)carve((size_t)8192 * 2);
    short*    hA     = (short*)carve((size_t)N * 128 * 2);
    short*    hB     = (short*)carve((size_t)N * 128 * 2);
    short*    featb  = (short*)carve((size_t)3 * N * 128 * 2);

    // weight prep + input conversion
    k_wprep<<<(6 * 16384 + 255) / 256, 256, 0, stream>>>(Ws, Wtg);
    k_wprep2<<<32, 256, 0, stream>>>(clf_W, Wcb);
    k_cvt<<<2048, 256, 0, stream>>>(feat_in, hA, N * 128);

    // CSR build via binned sort
    hipMemsetAsync(bcnt, 0, (size_t)3 * NB * 4, stream);
    dim3 gchunk((E + 4095) / 4096, 3);
    k_bhist<<<gchunk, 256, 0, stream>>>(dst, bcnt);
    k_bscan<<<3, 64, 0, stream>>>(bcnt, bptr, bcur);
    k_bin<<<gchunk, 256, 0, stream>>>(src, dst, bcur, ebin);
    dim3 gbkt(NB, 3);
    k_nhist<<<gbkt, 256, 0, stream>>>(ebin, bptr, rowptr);
    k_scat2<<<gbkt, 256, 0, stream>>>(ebin, bptr, rowptr, csrc);

    int gq = (N + 3) / 4;
    for (int l = 0; l < 2; l++) {
        const short* hin = (l == 0) ? hA : hB;
        short* hout = (l == 0) ? hB : hA;
        k_gemm3<<<(N + 127) / 128, 256, 0, stream>>>(hin, Wtg + (size_t)l * 3 * 16384,
                                                     als + (size_t)l * 384, ars + (size_t)l * 384,
                                                     featb, elr, N);
        k_agg3<<<gq, 256, 0, stream>>>(featb, elr, rowptr, csrc,
                                       bs + (size_t)l * 384, hout, N);
    }

    // BN + classifier on hA (layer-2 output, relu'd bf16)
    hipMemsetAsync(bnsum, 0, 256 * 4, stream);
    k_bnstat<<<512, 256, 0, stream>>>(hA, bnsum, N);
    k_clf<<<(N + 127) / 128, 256, 0, stream>>>(hA, bnsum, bn_w, bn_b, Wcb, clf_b, out, N);
}

// Round 11
// 368.459 us; speedup vs baseline: 1.6769x; 1.2169x over previous
//
#include <hip/hip_runtime.h>
#include <hip/hip_bf16.h>

#define N_NODES 100000
#define N_EDGES 500000
#define HID 128
#define NEG_SLOPE 0.2f
#define NB 98           // buckets of 1024 nodes: ceil(100000/1024)

typedef __attribute__((ext_vector_type(8))) short short8v;
typedef __attribute__((ext_vector_type(4))) short short4v;
typedef __attribute__((ext_vector_type(4))) float f32x4;

__device__ __forceinline__ short f2bf(float x) {
    union { float f; unsigned u; } v; v.f = x;
    unsigned r = v.u + 0x7fff + ((v.u >> 16) & 1);  // RNE
    return (short)(r >> 16);
}
__device__ __forceinline__ float bflo(unsigned u) {
    union { unsigned x; float f; } c; c.x = u << 16; return c.f;
}
__device__ __forceinline__ float bfhi(unsigned u) {
    union { unsigned x; float f; } c; c.x = u & 0xffff0000u; return c.f;
}
__device__ __forceinline__ float bfs(short s) {
    union { unsigned x; float f; } c; c.x = ((unsigned)(unsigned short)s) << 16; return c.f;
}
__device__ __forceinline__ float asf(unsigned u) {
    union { unsigned x; float f; } c; c.x = u; return c.f;
}

// ---------------- CSR build: binned two-level sort ----------------

__global__ __launch_bounds__(256) void k_bhist(const int* __restrict__ dst, int* __restrict__ bcnt) {
    int r = blockIdx.y, tid = threadIdx.x;
    int base = blockIdx.x * 4096;
    __shared__ int h[128];
    if (tid < 128) h[tid] = 0;
    __syncthreads();
    size_t eb = (size_t)r * N_EDGES;
    int lim = min(base + 4096, N_EDGES);
    for (int e = base + tid; e < lim; e += 256) atomicAdd(&h[dst[eb + e] >> 10], 1);
    __syncthreads();
    if (tid < NB && h[tid]) atomicAdd(&bcnt[r * NB + tid], h[tid]);
}

__global__ void k_bscan(const int* __restrict__ bcnt, int* __restrict__ bptr, int* __restrict__ bcur) {
    int r = blockIdx.x, lane = threadIdx.x;
    int carry = 0;
    for (int base = 0; base < NB; base += 64) {
        int i = base + lane;
        int c = (i < NB) ? bcnt[r * NB + i] : 0;
        int v = c;
        #pragma unroll
        for (int d = 1; d < 64; d <<= 1) { int t = __shfl_up(v, d); if (lane >= d) v += t; }
        int excl = carry + v - c;
        if (i < NB) { bptr[r * (NB + 1) + i] = excl; bcur[r * NB + i] = excl; }
        carry += __shfl(v, 63);
    }
    if (lane == 0) bptr[r * (NB + 1) + NB] = carry;
}

// bin edges into bucket regions of ebin packed as ((dst&1023)<<17 | src)
__global__ __launch_bounds__(256) void k_bin(const int* __restrict__ src, const int* __restrict__ dst,
                                             int* __restrict__ bcur, unsigned* __restrict__ ebin) {
    int r = blockIdx.y, tid = threadIdx.x;
    int base = blockIdx.x * 4096;
    __shared__ int cnt[128], incl[128], gb[128], wcur[128];
    __shared__ uint2 stage[4096];
    if (tid < 128) cnt[tid] = 0;
    __syncthreads();
    int myd[16], mys[16];
    size_t eb = (size_t)r * N_EDGES;
    #pragma unroll
    for (int i = 0; i < 16; i++) {
        int e = base + i * 256 + tid;
        if (e < N_EDGES) {
            int d = dst[eb + e];
            myd[i] = d; mys[i] = src[eb + e];
            atomicAdd(&cnt[d >> 10], 1);
        } else myd[i] = -1;
    }
    __syncthreads();
    if (tid < 128) incl[tid] = cnt[tid];
    __syncthreads();
    for (int d = 1; d < 128; d <<= 1) {
        int t = 0;
        if (tid < 128 && tid >= d) t = incl[tid - d];
        __syncthreads();
        if (tid < 128 && tid >= d) incl[tid] += t;
        __syncthreads();
    }
    if (tid < 128) {
        wcur[tid] = incl[tid] - cnt[tid];
        gb[tid] = (tid < NB && cnt[tid] > 0) ? atomicAdd(&bcur[r * NB + tid], cnt[tid]) : 0;
    }
    __syncthreads();
    #pragma unroll
    for (int i = 0; i < 16; i++) {
        if (myd[i] >= 0) {
            int bkt = myd[i] >> 10;
            int p = atomicAdd(&wcur[bkt], 1);
            stage[p] = make_uint2((unsigned)myd[i], (unsigned)mys[i]);
        }
    }
    __syncthreads();
    int tot = min(4096, N_EDGES - base);
    for (int i = tid; i < tot; i += 256) {
        uint2 u = stage[i];
        int bkt = (int)(u.x >> 10);
        int ex = incl[bkt] - cnt[bkt];
        ebin[eb + gb[bkt] + (i - ex)] = ((u.x & 1023u) << 17) | u.y;
    }
}

__global__ __launch_bounds__(256) void k_nhist(const unsigned* __restrict__ ebin,
                                               const int* __restrict__ bptr,
                                               int* __restrict__ rowptr) {
    int b = blockIdx.x, r = blockIdx.y, tid = threadIdx.x;
    __shared__ int cnt[1024];
    __shared__ int wsum[4];
    for (int i = tid; i < 1024; i += 256) cnt[i] = 0;
    __syncthreads();
    int es = bptr[r * (NB + 1) + b], ee = bptr[r * (NB + 1) + b + 1];
    size_t eb = (size_t)r * N_EDGES;
    for (int i = es + tid; i < ee; i += 256) atomicAdd(&cnt[(ebin[eb + i] >> 17) & 1023u], 1);
    __syncthreads();
    int b4 = tid * 4;
    int c0 = cnt[b4], c1 = cnt[b4 + 1], c2 = cnt[b4 + 2], c3 = cnt[b4 + 3];
    int ts = c0 + c1 + c2 + c3;
    int lane = tid & 63, wid = tid >> 6;
    int v = ts;
    #pragma unroll
    for (int d = 1; d < 64; d <<= 1) { int t = __shfl_up(v, d); if (lane >= d) v += t; }
    if (lane == 63) wsum[wid] = v;
    __syncthreads();
    int woff = 0;
    for (int w = 0; w < wid; w++) woff += wsum[w];
    int p = woff + v - ts;
    int node0 = b << 10;
    int rp = r * (N_NODES + 1);
    int nd;
    nd = node0 + b4;     if (nd < N_NODES) rowptr[rp + nd] = es + p; p += c0;
    nd = node0 + b4 + 1; if (nd < N_NODES) rowptr[rp + nd] = es + p; p += c1;
    nd = node0 + b4 + 2; if (nd < N_NODES) rowptr[rp + nd] = es + p; p += c2;
    nd = node0 + b4 + 3; if (nd < N_NODES) rowptr[rp + nd] = es + p;
    if (b == NB - 1 && tid == 0) rowptr[rp + N_NODES] = bptr[r * (NB + 1) + NB];
}

__global__ __launch_bounds__(256) void k_scat2(const unsigned* __restrict__ ebin,
                                               const int* __restrict__ bptr,
                                               const int* __restrict__ rowptr,
                                               int* __restrict__ csrc) {
    int b = blockIdx.x, r = blockIdx.y, tid = threadIdx.x;
    __shared__ int cnt[1024];
    __shared__ int rloc[1024];
    __shared__ int stage[8192];
    int node0 = b << 10;
    int rp = r * (N_NODES + 1);
    int rs = rowptr[rp + node0];
    for (int i = tid; i < 1024; i += 256) {
        cnt[i] = 0;
        int nd = node0 + i; if (nd > N_NODES) nd = N_NODES;
        rloc[i] = rowptr[rp + nd] - rs;
    }
    __syncthreads();
    int es = bptr[r * (NB + 1) + b], ee = bptr[r * (NB + 1) + b + 1];
    int sz = ee - es;
    size_t eb = (size_t)r * N_EDGES;
    if (sz <= 8192) {
        for (int i = es + tid; i < ee; i += 256) {
            unsigned u = ebin[eb + i];
            int dl = (int)((u >> 17) & 1023u);
            int rk = atomicAdd(&cnt[dl], 1);
            stage[rloc[dl] + rk] = (int)(u & 0x1FFFFu);
        }
        __syncthreads();
        for (int i = tid; i < sz; i += 256) csrc[eb + rs + i] = stage[i];
    } else {
        for (int i = es + tid; i < ee; i += 256) {
            unsigned u = ebin[eb + i];
            int dl = (int)((u >> 17) & 1023u);
            int rk = atomicAdd(&cnt[dl], 1);
            csrc[eb + rs + rloc[dl] + rk] = (int)(u & 0x1FFFFu);
        }
    }
}

// ---------------- W prep: f32 [k][col] -> bf16 [col][k ^ ((col&7)<<3)] ----------------
__global__ void k_wprep(const float* __restrict__ Ws, short* __restrict__ Wt) {
    int i = blockIdx.x * blockDim.x + threadIdx.x;
    if (i < 6 * 16384) {
        int lr = i >> 14, rem = i & 16383, k = rem >> 7, col = rem & 127;
        Wt[lr * 16384 + col * 128 + (k ^ ((col & 7) << 3))] = f2bf(Ws[i]);
    }
}

// clf_W f32 [128 k][64 col] -> bf16 [col][k ^ ((col&7)<<3)]
__global__ void k_wprep2(const float* __restrict__ Wc, short* __restrict__ Wcb) {
    int i = blockIdx.x * blockDim.x + threadIdx.x;
    if (i < 8192) {
        int k = i >> 6, col = i & 63;
        Wcb[col * 128 + (k ^ ((col & 7) << 3))] = f2bf(Wc[i]);
    }
}

// ---------------- f32 -> bf16 bulk convert ----------------
__global__ void k_cvt(const float* __restrict__ in, short* __restrict__ out, int n) {
    int i = blockIdx.x * blockDim.x + threadIdx.x;
    int stride = gridDim.x * blockDim.x;
    for (int base = i * 8; base < n; base += stride * 8) {
        float4 x = *(const float4*)(in + base);
        float4 y = *(const float4*)(in + base + 4);
        short8v o;
        o[0] = f2bf(x.x); o[1] = f2bf(x.y); o[2] = f2bf(x.z); o[3] = f2bf(x.w);
        o[4] = f2bf(y.x); o[5] = f2bf(y.y); o[6] = f2bf(y.z); o[7] = f2bf(y.w);
        *(short8v*)(out + base) = o;
    }
}

// ---------------- MFMA GEMM over 3 relations in one dispatch: featb[r] bf16 + fused el/er ----------------
__global__ __launch_bounds__(256) void k_gemm3(const short* __restrict__ Abf,
                                               const short* __restrict__ Wt3,    // 3 x 16384, pre-swizzled
                                               const float* __restrict__ al3,    // [3][128]
                                               const float* __restrict__ ar3,    // [3][128]
                                               short* __restrict__ featb,        // [3][N*128]
                                               float4* __restrict__ elr,         // [3][N]
                                               int nrows) {
    __shared__ __align__(16) short Wl[128 * 128];
    int tid = threadIdx.x;
    int lane = tid & 63, wid = tid >> 6;
    int q = lane >> 4, j = lane & 15;
    int rowbase = blockIdx.x * 128 + wid * 32;

    // A fragments once (shared by all 3 relations)
    short8v a[2][4];
    #pragma unroll
    for (int rb = 0; rb < 2; rb++) {
        int row = rowbase + rb * 16 + j;
        const short* ap = Abf + (size_t)row * 128 + q * 8;
        bool ok = row < nrows;
        #pragma unroll
        for (int kk = 0; kk < 4; kk++)
            a[rb][kk] = ok ? *(const short8v*)(ap + kk * 32) : (short8v)0;
    }

    for (int cr = 0; cr < 3; cr++) {
        if (cr) __syncthreads();   // all waves done reading Wl before overwrite
        {
            const float4* srcv = (const float4*)(Wt3 + cr * 16384);
            float4* dstv = (float4*)Wl;
            #pragma unroll
            for (int i = 0; i < 8; i++) dstv[tid + i * 256] = srcv[tid + i * 256];
        }
        float alv[8], arv[8];
        #pragma unroll
        for (int cb = 0; cb < 8; cb++) {
            alv[cb] = al3[cr * 128 + cb * 16 + j];
            arv[cb] = ar3[cr * 128 + cb * 16 + j];
        }
        __syncthreads();

        f32x4 acc[2][8] = {};
        #pragma unroll
        for (int cb = 0; cb < 8; cb++) {
            int col = cb * 16 + j;
            const short* wp = Wl + col * 128;
            int sw = (col & 7) << 3;
            #pragma unroll
            for (int kk = 0; kk < 4; kk++) {
                short8v b = *(const short8v*)(wp + ((kk * 32 + q * 8) ^ sw));
                acc[0][cb] = __builtin_amdgcn_mfma_f32_16x16x32_bf16(a[0][kk], b, acc[0][cb], 0, 0, 0);
                acc[1][cb] = __builtin_amdgcn_mfma_f32_16x16x32_bf16(a[1][kk], b, acc[1][cb], 0, 0, 0);
            }
        }

        short* outB = featb + (size_t)cr * N_NODES * 128;
        #pragma unroll
        for (int rb = 0; rb < 2; rb++) {
            int row0 = rowbase + rb * 16 + q * 4;
            #pragma unroll
            for (int reg = 0; reg < 4; reg++) {
                int row = row0 + reg;
                if (row < nrows) {
                    short* op = outB + (size_t)row * 128 + j;
                    #pragma unroll
                    for (int cb = 0; cb < 8; cb++) op[cb * 16] = f2bf(acc[rb][cb][reg]);
                }
            }
        }

        // fused el/er
        float4* elro = elr + (size_t)cr * N_NODES;
        #pragma unroll
        for (int rb = 0; rb < 2; rb++) {
            float e0[4], e1[4], r0[4], r1[4];
            #pragma unroll
            for (int reg = 0; reg < 4; reg++) {
                float se0 = 0.f, se1 = 0.f, sr0 = 0.f, sr1 = 0.f;
                #pragma unroll
                for (int cb = 0; cb < 4; cb++) {
                    se0 += acc[rb][cb][reg] * alv[cb];
                    sr0 += acc[rb][cb][reg] * arv[cb];
                    se1 += acc[rb][cb + 4][reg] * alv[cb + 4];
                    sr1 += acc[rb][cb + 4][reg] * arv[cb + 4];
                }
                #pragma unroll
                for (int off = 1; off < 16; off <<= 1) {
                    se0 += __shfl_xor(se0, off);
                    se1 += __shfl_xor(se1, off);
                    sr0 += __shfl_xor(sr0, off);
                    sr1 += __shfl_xor(sr1, off);
                }
                e0[reg] = se0; e1[reg] = se1; r0[reg] = sr0; r1[reg] = sr1;
            }
            if (j < 4) {
                int row = rowbase + rb * 16 + q * 4 + j;
                if (row < nrows) {
                    float4 v;
                    v.x = j == 0 ? e0[0] : j == 1 ? e0[1] : j == 2 ? e0[2] : e0[3];
                    v.y = j == 0 ? e1[0] : j == 1 ? e1[1] : j == 2 ? e1[2] : e1[3];
                    v.z = j == 0 ? r0[0] : j == 1 ? r0[1] : j == 2 ? r0[2] : r0[3];
                    v.w = j == 0 ? r1[0] : j == 1 ? r1[1] : j == 2 ? r1[2] : r1[3];
                    elro[row] = v;
                }
            }
        }
    }
}

// ---------------- merged 3-relation softmax + gather-aggregate (wave per dst node) ----------------
// Branchless 4-wide chunked gather loops: invalid lanes carry p=0, sv=0 so chunks need no guards.
// no-max softmax; p packed bf16-pair -> one readlane broadcast per edge; relu'd bf16 output.
__global__ __launch_bounds__(256) void k_agg3(const short* __restrict__ feat,   // [3][N*128]
                                              const float4* __restrict__ elr,   // [3][N]
                                              const int* __restrict__ rowptr,   // [3][N+1]
                                              const int* __restrict__ csrc,     // [3][E]
                                              const float* __restrict__ bias,   // [3][128]
                                              short* __restrict__ outB, int nrows) {
    int wid = threadIdx.x >> 6, lane = threadIdx.x & 63;
    int v = (blockIdx.x << 2) + wid;
    if (v >= nrows) return;
    int c0 = lane << 1;

    int beg[3], end[3], bc[3];
    #pragma unroll
    for (int r = 0; r < 3; r++) {
        beg[r] = rowptr[r * (N_NODES + 1) + v];
        end[r] = rowptr[r * (N_NODES + 1) + v + 1];
        bc[r] = min(64, end[r] - beg[r]);
    }
    float4 ev[3];
    #pragma unroll
    for (int r = 0; r < 3; r++) ev[r] = elr[(size_t)r * N_NODES + v];

    int sv[3]; unsigned pk[3];
    #pragma unroll
    for (int r = 0; r < 3; r++)
        sv[r] = (lane < end[r] - beg[r]) ? csrc[(size_t)r * N_EDGES + beg[r] + lane] : 0;
    #pragma unroll
    for (int r = 0; r < 3; r++) {
        float4 es = elr[(size_t)r * N_NODES + sv[r]];
        float e0 = es.x + ev[r].z; e0 = e0 >= 0.f ? e0 : NEG_SLOPE * e0;
        float e1 = es.y + ev[r].w; e1 = e1 >= 0.f ? e1 : NEG_SLOPE * e1;
        bool val = lane < (end[r] - beg[r]);
        float p0 = val ? __expf(e0) : 0.f;
        float p1 = val ? __expf(e1) : 0.f;
        pk[r] = ((unsigned)(unsigned short)f2bf(p0)) |
                (((unsigned)(unsigned short)f2bf(p1)) << 16);
    }

    float a0[3], a1[3], sp[3];
    bool lo = lane < 32;

    #pragma unroll
    for (int r = 0; r < 3; r++) {
        const short* fb = feat + (size_t)r * (N_NODES * 128);
        int nb = bc[r];
        float sA = 0.f, xa = 0.f, xb = 0.f, ya = 0.f, yb = 0.f;
        for (int j0 = 0; j0 < nb; j0 += 4) {
            int s0 = __builtin_amdgcn_readlane(sv[r], j0);
            int s1 = __builtin_amdgcn_readlane(sv[r], j0 + 1);
            int s2 = __builtin_amdgcn_readlane(sv[r], j0 + 2);
            int s3 = __builtin_amdgcn_readlane(sv[r], j0 + 3);
            unsigned b0 = (unsigned)__builtin_amdgcn_readlane((int)pk[r], j0);
            unsigned b1 = (unsigned)__builtin_amdgcn_readlane((int)pk[r], j0 + 1);
            unsigned b2 = (unsigned)__builtin_amdgcn_readlane((int)pk[r], j0 + 2);
            unsigned b3 = (unsigned)__builtin_amdgcn_readlane((int)pk[r], j0 + 3);
            unsigned u0 = *(const unsigned*)(fb + ((size_t)(unsigned)s0 << 7) + c0);
            unsigned u1 = *(const unsigned*)(fb + ((size_t)(unsigned)s1 << 7) + c0);
            unsigned u2 = *(const unsigned*)(fb + ((size_t)(unsigned)s2 << 7) + c0);
            unsigned u3 = *(const unsigned*)(fb + ((size_t)(unsigned)s3 << 7) + c0);
            float p0 = asf(lo ? (b0 << 16) : (b0 & 0xffff0000u));
            float p1 = asf(lo ? (b1 << 16) : (b1 & 0xffff0000u));
            float p2 = asf(lo ? (b2 << 16) : (b2 & 0xffff0000u));
            float p3 = asf(lo ? (b3 << 16) : (b3 & 0xffff0000u));
            sA += (p0 + p1) + (p2 + p3);
            xa += p0 * bflo(u0); xb += p0 * bfhi(u0);
            ya += p1 * bflo(u1); yb += p1 * bfhi(u1);
            xa += p2 * bflo(u2); xb += p2 * bfhi(u2);
            ya += p3 * bflo(u3); yb += p3 * bfhi(u3);
        }
        sp[r] = sA; a0[r] = xa + ya; a1[r] = xb + yb;
    }

    // rare tail: degree > 64
    #pragma unroll
    for (int r = 0; r < 3; r++) {
        for (int base = beg[r] + 64; base < end[r]; base += 64) {
            int idx = base + lane;
            bool val = idx < end[r];
            int sv2 = val ? csrc[(size_t)r * N_EDGES + idx] : 0;
            float4 es = elr[(size_t)r * N_NODES + sv2];
            float e0 = es.x + ev[r].z; e0 = e0 >= 0.f ? e0 : NEG_SLOPE * e0;
            float e1 = es.y + ev[r].w; e1 = e1 >= 0.f ? e1 : NEG_SLOPE * e1;
            float q0v = val ? __expf(e0) : 0.f;
            float q1v = val ? __expf(e1) : 0.f;
            int bc2 = min(64, end[r] - base);
            for (int k = 0; k < bc2; k++) {
                int ss = __builtin_amdgcn_readlane(sv2, k);
                float q0 = asf((unsigned)__builtin_amdgcn_readlane((int)__float_as_uint(q0v), k));
                float q1 = asf((unsigned)__builtin_amdgcn_readlane((int)__float_as_uint(q1v), k));
                float pp = lo ? q0 : q1;
                unsigned u = *(const unsigned*)(feat + (size_t)r * N_NODES * 128 + ((size_t)ss << 7) + c0);
                sp[r] += pp;
                a0[r] += pp * bflo(u);
                a1[r] += pp * bfhi(u);
            }
        }
    }

    float t0 = bias[c0] + bias[128 + c0] + bias[256 + c0];
    float t1 = bias[c0 + 1] + bias[128 + c0 + 1] + bias[256 + c0 + 1];
    #pragma unroll
    for (int r = 0; r < 3; r++) {
        float inv = sp[r] > 0.f ? 1.0f / sp[r] : 0.f;
        t0 += a0[r] * inv;
        t1 += a1[r] * inv;
    }
    unsigned pko = ((unsigned)(unsigned short)f2bf(fmaxf(t0, 0.f))) |
                   (((unsigned)(unsigned short)f2bf(fmaxf(t1, 0.f))) << 16);
    *(unsigned*)(outB + (size_t)v * 128 + c0) = pko;
}

// ---------------- BN stats (bf16 relu'd input, vectorized) ----------------
__global__ __launch_bounds__(256) void k_bnstat(const short* __restrict__ h,
                                                float* __restrict__ sums, int nrows) {
    int tid = threadIdx.x;
    int cg = tid & 15, rgrp = tid >> 4;
    float s[8] = {}, q[8] = {};
    for (int row = blockIdx.x * 16 + rgrp; row < nrows; row += gridDim.x * 16) {
        short8v u = *(const short8v*)(h + (size_t)row * 128 + cg * 8);
        #pragma unroll
        for (int i = 0; i < 8; i++) {
            float x = bfs(u[i]);
            s[i] += x; q[i] += x * x;
        }
    }
    __shared__ float ls[16][128];
    __shared__ float lq[16][128];
    #pragma unroll
    for (int i = 0; i < 8; i++) { ls[rgrp][cg * 8 + i] = s[i]; lq[rgrp][cg * 8 + i] = q[i]; }
    __syncthreads();
    int t = tid;
    if (t < 128) {
        float ts = 0.f, tq = 0.f;
        #pragma unroll
        for (int g = 0; g < 16; g++) { ts += ls[g][t]; tq += lq[g][t]; }
        atomicAdd(&sums[t], ts);
        atomicAdd(&sums[128 + t], tq);
    }
}

// ---------------- classifier: BN-normalize (input pre-relu'd bf16) -> MFMA GEMM [N,128]x[128,64] ----------------
__global__ __launch_bounds__(256) void k_clf(const short* __restrict__ h,
                                             const float* __restrict__ sums,
                                             const float* __restrict__ bn_w,
                                             const float* __restrict__ bn_b,
                                             const short* __restrict__ Wcb,
                                             const float* __restrict__ cbias,
                                             float* __restrict__ out, int nrows) {
    __shared__ __align__(16) short Wl[64 * 128];
    __shared__ float2 bnp[128];
    int tid = threadIdx.x;
    {
        const float4* srcv = (const float4*)Wcb;
        float4* dstv = (float4*)Wl;
        #pragma unroll
        for (int i = 0; i < 4; i++) dstv[tid + i * 256] = srcv[tid + i * 256];
    }
    if (tid < 128) {
        float mu = sums[tid] / (float)nrows;
        float var = sums[128 + tid] / (float)nrows - mu * mu;
        float rs = rsqrtf(var + 1e-5f);
        float sc = bn_w[tid] * rs;
        bnp[tid] = make_float2(sc, bn_b[tid] - mu * sc);
    }
    __syncthreads();

    int lane = tid & 63, wid = tid >> 6;
    int q = lane >> 4, j = lane & 15;
    int rowbase = blockIdx.x * 128 + wid * 32;

    float cbv[4];
    #pragma unroll
    for (int cb = 0; cb < 4; cb++) cbv[cb] = cbias[cb * 16 + j];

    short8v a[2][4];
    #pragma unroll
    for (int rb = 0; rb < 2; rb++) {
        int row = rowbase + rb * 16 + j;
        bool ok = row < nrows;
        const short* hp = h + (size_t)row * 128 + q * 8;
        #pragma unroll
        for (int kk = 0; kk < 4; kk++) {
            short8v u = ok ? *(const short8v*)(hp + kk * 32) : (short8v)0;
            int k0 = kk * 32 + q * 8;
            short8v av;
            #pragma unroll
            for (int i = 0; i < 8; i++) {
                float2 bp = bnp[k0 + i];
                av[i] = f2bf(bfs(u[i]) * bp.x + bp.y);
            }
            a[rb][kk] = av;
        }
    }

    f32x4 acc[2][4] = {};
    #pragma unroll
    for (int cb = 0; cb < 4; cb++) {
        int col = cb * 16 + j;
        const short* wp = Wl + col * 128;
        int sw = (col & 7) << 3;
        #pragma unroll
        for (int kk = 0; kk < 4; kk++) {
            short8v b = *(const short8v*)(wp + ((kk * 32 + q * 8) ^ sw));
            acc[0][cb] = __builtin_amdgcn_mfma_f32_16x16x32_bf16(a[0][kk], b, acc[0][cb], 0, 0, 0);
            acc[1][cb] = __builtin_amdgcn_mfma_f32_16x16x32_bf16(a[1][kk], b, acc[1][cb], 0, 0, 0);
        }
    }

    #pragma unroll
    for (int rb = 0; rb < 2; rb++) {
        int row0 = rowbase + rb * 16 + q * 4;
        #pragma unroll
        for (int reg = 0; reg < 4; reg++) {
            int row = row0 + reg;
            if (row < nrows) {
                float* op = out + (size_t)row * 64 + j;
                #pragma unroll
                for (int cb = 0; cb < 4; cb++) op[cb * 16] = acc[rb][cb][reg] + cbv[cb];
            }
        }
    }
}

// ---------------- launch ----------------

extern "C" void kernel_launch(void* const* d_in, const int* in_sizes, int n_in,
                              void* d_out, int out_size, void* d_ws, size_t ws_size,
                              hipStream_t stream) {
    (void)in_sizes; (void)n_in; (void)out_size; (void)ws_size;
    const float* feat_in = (const float*)d_in[0];
    const float* Ws      = (const float*)d_in[1];
    const float* als     = (const float*)d_in[2];
    const float* ars     = (const float*)d_in[3];
    const float* bs      = (const float*)d_in[4];
    const float* bn_w    = (const float*)d_in[5];
    const float* bn_b    = (const float*)d_in[6];
    const float* clf_W   = (const float*)d_in[7];
    const float* clf_b   = (const float*)d_in[8];
    const int*   src     = (const int*)d_in[9];
    const int*   dst     = (const int*)d_in[10];
    float* out = (float*)d_out;

    const int N = N_NODES, E = N_EDGES;
    char* p = (char*)d_ws;
    auto carve = [&](size_t bytes) { char* q = p; p += (bytes + 255) & ~255ULL; return q; };
    int*      bcnt   = (int*)carve((size_t)3 * NB * 4);
    int*      bptr   = (int*)carve((size_t)3 * (NB + 1) * 4);
    int*      bcur   = (int*)carve((size_t)3 * NB * 4);
    int*      rowptr = (int*)carve((size_t)3 * (N + 1) * 4);
    int*      csrc   = (int*)carve((size_t)3 * E * 4);
    unsigned* ebin   = (unsigned*)carve((size_t)3 * E * 4);
    float4*   elr    = (float4*)carve((size_t)3 * N * 16);
    float*    bnsum  = (float*)carve(256 * 4);
    short*    Wtg    = (short*)carve((size_t)6 * 16384 * 2);
    short*    Wcb    = (short*)carve((size_t)8192 * 2);
    short*    hA     = (short*)carve((size_t)N * 128 * 2);
    short*    hB     = (short*)carve((size_t)N * 128 * 2);
    short*    featb  = (short*)carve((size_t)3 * N * 128 * 2);

    // weight prep + input conversion
    k_wprep<<<(6 * 16384 + 255) / 256, 256, 0, stream>>>(Ws, Wtg);
    k_wprep2<<<32, 256, 0, stream>>>(clf_W, Wcb);
    k_cvt<<<2048, 256, 0, stream>>>(feat_in, hA, N * 128);

    // CSR build via binned sort
    hipMemsetAsync(bcnt, 0, (size_t)3 * NB * 4, stream);
    dim3 gchunk((E + 4095) / 4096, 3);
    k_bhist<<<gchunk, 256, 0, stream>>>(dst, bcnt);
    k_bscan<<<3, 64, 0, stream>>>(bcnt, bptr, bcur);
    k_bin<<<gchunk, 256, 0, stream>>>(src, dst, bcur, ebin);
    dim3 gbkt(NB, 3);
    k_nhist<<<gbkt, 256, 0, stream>>>(ebin, bptr, rowptr);
    k_scat2<<<gbkt, 256, 0, stream>>>(ebin, bptr, rowptr, csrc);

    int gq = (N + 3) / 4;
    for (int l = 0; l < 2; l++) {
        const short* hin = (l == 0) ? hA : hB;
        short* hout = (l == 0) ? hB : hA;
        k_gemm3<<<(N + 127) / 128, 256, 0, stream>>>(hin, Wtg + (size_t)l * 3 * 16384,
                                                     als + (size_t)l * 384, ars + (size_t)l * 384,
                                                     featb, elr, N);
        k_agg3<<<gq, 256, 0, stream>>>(featb, elr, rowptr, csrc,
                                       bs + (size_t)l * 384, hout, N);
    }

    // BN + classifier on hA (layer-2 output, relu'd bf16)
    hipMemsetAsync(bnsum, 0, 256 * 4, stream);
    k_bnstat<<<512, 256, 0, stream>>>(hA, bnsum, N);
    k_clf<<<(N + 127) / 128, 256, 0, stream>>>(hA, bnsum, bn_w, bn_b, Wcb, clf_b, out, N);
}